// Round 4
// baseline (313.923 us; speedup 1.0000x reference)
//
#include <hip/hip_runtime.h>
#include <math.h>

#define LATENT 1024
#define QDIM 256
#define NW 196608           // LATENT * CPG * K
#define BI 128
#define BC 32
#define TT 50
#define REGIONS 36
#define NGROUPS 16
#define CPG 64
#define NEG 0.1f

typedef __attribute__((ext_vector_type(8))) short short8;
typedef __attribute__((ext_vector_type(16))) float f32x16;

__device__ __forceinline__ float leakyf(float x){ return x > 0.f ? x : NEG * x; }

__device__ __forceinline__ unsigned short f2bf(float x){
    union { float f; unsigned int u; } v; v.f = x;
    unsigned int r = v.u + 0x7FFFu + ((v.u >> 16) & 1u);   // RNE
    return (unsigned short)(r >> 16);
}

// ---------------------------------------------------------------------------
// Kernel 1a: masked mean over words + gate + ||cap_repr||. grid=32, 256 thr.
// ---------------------------------------------------------------------------
__global__ __launch_bounds__(256) void cap_mean_kernel(
    const float* __restrict__ cap_embed, const int* __restrict__ lens,
    float* __restrict__ cap_repr, float* __restrict__ cap_act,
    float* __restrict__ norm_capr)
{
    const int n = blockIdx.x;
    const int len = lens[n];
    const float invl = 1.f / (float)len;
    const int c4 = threadIdx.x;            // 4 channels per thread
    const float* base = cap_embed + (size_t)n * TT * LATENT + c4 * 4;
    float4 s = {0.f, 0.f, 0.f, 0.f};
    for (int t = 0; t < len; ++t) {
        const float4 v = *reinterpret_cast<const float4*>(base + (size_t)t * LATENT);
        s.x += v.x; s.y += v.y; s.z += v.z; s.w += v.w;
    }
    float4 m = {s.x * invl, s.y * invl, s.z * invl, s.w * invl};
    *reinterpret_cast<float4*>(cap_repr + n * LATENT + c4 * 4) = m;
    float4 a = {leakyf(m.x), leakyf(m.y), leakyf(m.z), leakyf(m.w)};
    *reinterpret_cast<float4*>(cap_act + n * LATENT + c4 * 4) = a;
    float ss = m.x*m.x + m.y*m.y + m.z*m.z + m.w*m.w;
    #pragma unroll
    for (int off = 32; off; off >>= 1) ss += __shfl_xor(ss, off);
    __shared__ float red4[4];
    if ((threadIdx.x & 63) == 0) red4[threadIdx.x >> 6] = ss;
    __syncthreads();
    if (threadIdx.x == 0) norm_capr[n] = sqrtf(red4[0] + red4[1] + red4[2] + red4[3]);
}

// ---------------------------------------------------------------------------
// Kernel 1b: qT[r][n] = cap_repr[n,:] @ red_w[:,r] + red_b[r]
// grid=(8 colgroups, 32 n), 256 thr = 32 cols x 8 K-slices.
// ---------------------------------------------------------------------------
__global__ __launch_bounds__(256) void q_kernel(
    const float* __restrict__ cap_repr, const float* __restrict__ red_w,
    const float* __restrict__ red_b, float* __restrict__ qT)
{
    const int cg = blockIdx.x, n = blockIdx.y;
    const int col = threadIdx.x & 31, ks = threadIdx.x >> 5;
    const float* cr = cap_repr + n * LATENT;
    float p = 0.f;
    const int r0 = ks * 128;
    for (int r = r0; r < r0 + 128; ++r)
        p = fmaf(cr[r], red_w[(size_t)r * QDIM + cg * 32 + col], p);
    __shared__ float part[256];
    part[threadIdx.x] = p;
    __syncthreads();
    if (threadIdx.x < 32) {
        float s = red_b[cg * 32 + col];
        #pragma unroll
        for (int k = 0; k < 8; ++k) s += part[k * 32 + col];
        qT[(cg * 32 + col) * 32 + n] = s;
    }
}

// ---------------------------------------------------------------------------
// Kernel 2: img f32 -> bf16 (same layout)
// ---------------------------------------------------------------------------
__global__ __launch_bounds__(256) void img2bf_kernel(
    const float* __restrict__ in, unsigned short* __restrict__ out)
{
    const size_t base = ((size_t)blockIdx.x * 256 + threadIdx.x) * 8;
    const float4 u = *reinterpret_cast<const float4*>(in + base);
    const float4 v = *reinterpret_cast<const float4*>(in + base + 4);
    unsigned short r[8];
    r[0]=f2bf(u.x); r[1]=f2bf(u.y); r[2]=f2bf(u.z); r[3]=f2bf(u.w);
    r[4]=f2bf(v.x); r[5]=f2bf(v.y); r[6]=f2bf(v.z); r[7]=f2bf(v.w);
    *reinterpret_cast<int4*>(out + base) = *reinterpret_cast<const int4*>(r);
}

// ---------------------------------------------------------------------------
// Kernel 3: wgen4 — block = one (g,o) slice (192 cols = 64 (i)-triples),
// 192 thr, grid 1024 (=16g x 64o). q read via wave-uniform global loads
// (scalarized to s_load; no LDS traffic in the GEMM loop).
// Writes Wp2L with the conv B-swizzle pre-baked:
//   elem[(n*16+g)*12288 + (k*64+o)*64 + (i ^ ((o&7)<<3))]
// ---------------------------------------------------------------------------
__global__ __launch_bounds__(192) void wgen4_kernel(
    const float* __restrict__ qT, const float* __restrict__ proj_w,
    const float* __restrict__ proj_b, unsigned short* __restrict__ Wp2L)
{
    __shared__ float L[192 * 33];
    const int tid = threadIdx.x;
    const int col = blockIdx.x * 192 + tid;
    float acc[32];
    #pragma unroll
    for (int n2 = 0; n2 < 32; ++n2) acc[n2] = 0.f;
    const float* pw = proj_w + col;
    #pragma unroll 4
    for (int r = 0; r < QDIM; ++r) {
        const float w = pw[(size_t)r * NW];
        const float* qr = qT + r * 32;     // uniform address -> s_load
        #pragma unroll
        for (int nb = 0; nb < 8; ++nb) {
            const float4 qv = *reinterpret_cast<const float4*>(qr + nb * 4);
            acc[nb*4+0] = fmaf(w, qv.x, acc[nb*4+0]);
            acc[nb*4+1] = fmaf(w, qv.y, acc[nb*4+1]);
            acc[nb*4+2] = fmaf(w, qv.z, acc[nb*4+2]);
            acc[nb*4+3] = fmaf(w, qv.w, acc[nb*4+3]);
        }
    }
    const float b = proj_b[col];
    #pragma unroll
    for (int n2 = 0; n2 < 32; ++n2) L[tid * 33 + n2] = acc[n2] + b;
    __syncthreads();
    const int g = blockIdx.x >> 6, o = blockIdx.x & 63;
    const int swz = (o & 7) << 3;
    for (int idx = tid; idx < 2048; idx += 192) {
        const int n = idx & 31, i = idx >> 5;
        const int c = i * 3;
        const float x0 = L[c * 33 + n], x1 = L[(c+1)*33 + n], x2 = L[(c+2)*33 + n];
        const float m = fmaxf(fmaxf(x0, x1), x2);
        const float e0 = expf(x0 - m), e1 = expf(x1 - m), e2 = expf(x2 - m);
        const float inv = 1.f / (e0 + e1 + e2);
        const size_t base = ((size_t)(n * 16 + g) * 3) * 4096 + o * 64 + (i ^ swz);
        Wp2L[base]        = f2bf(e0 * inv);
        Wp2L[base + 4096] = f2bf(e1 * inv);
        Wp2L[base + 8192] = f2bf(e2 * inv);
    }
}

// ---------------------------------------------------------------------------
// Kernel 4: conv3 — A-frags cached in registers across the 8-caption loop;
// B staged by identity copy from pre-swizzled Wp2L with register prefetch
// (async-STAGE split); epilogue via shfl-combine + per-wave Sw slices
// (no LDS atomics). 192 thr = 3 waves, launch_bounds(192,1) for VGPR room.
// ---------------------------------------------------------------------------
__global__ __launch_bounds__(192, 1) void conv3_kernel(
    const unsigned short* __restrict__ img_bf, const unsigned short* __restrict__ Wp2L,
    const float* __restrict__ cap_repr, const float* __restrict__ cap_act,
    float* __restrict__ part_dot, float* __restrict__ part_ss)
{
    const int g = blockIdx.x, bt = blockIdx.y, nq = blockIdx.z;
    const int b0 = bt * 8;
    __shared__ char Asm[8 * 38 * 128];   // [row=b*38+pos][64 bf16], swizzled
    __shared__ char Bsm[192 * 128];      // identity image of Wp2L slice
    __shared__ float Sw[3][8][64];       // per-wave partial sums
    const int tid = threadIdx.x;
    const int wv = tid >> 6, lane = tid & 63;
    const int lrow = lane & 31, khalf = lane >> 5;
    const int ioff = khalf * 16;

    for (int idx = tid; idx < 1536; idx += 192) ((float*)Sw)[idx] = 0.f;

    // stage A once (reused for 8 captions)
    const unsigned short* imgG = img_bf + (size_t)b0 * 36 * 1024 + g * 64;
    for (int idx = tid; idx < 2304; idx += 192) {
        const int row_img = idx >> 3, ch = idx & 7;
        const int bb = row_img / 36;
        const int l = row_img - bb * 36;
        const int4 v = *reinterpret_cast<const int4*>(imgG + (size_t)row_img * 1024 + ch * 8);
        const int arow = bb * 38 + l + 1;
        const int byte = (arow * 128 + ch * 16) ^ ((arow & 7) << 4);
        *reinterpret_cast<int4*>(Asm + byte) = v;
    }
    for (int idx = tid; idx < 128; idx += 192) {   // zero pad rows
        const int r = idx >> 3, ch = idx & 7;
        const int arow = (r >> 1) * 38 + (r & 1) * 37;
        const int byte = (arow * 128 + ch * 16) ^ ((arow & 7) << 4);
        int4 z; z.x = 0; z.y = 0; z.z = 0; z.w = 0;
        *reinterpret_cast<int4*>(Asm + byte) = z;
    }
    __syncthreads();

    // load all A-frags into registers: [mt][k][ks]
    int abase[3];
    #pragma unroll
    for (int mt = 0; mt < 3; ++mt) {
        const int r = wv * 96 + mt * 32 + lrow;
        const int bb = r / 36;
        abase[mt] = bb * 38 + (r - bb * 36);
    }
    short8 afr[3][3][4];
    #pragma unroll
    for (int mt = 0; mt < 3; ++mt)
        #pragma unroll
        for (int k = 0; k < 3; ++k)
            #pragma unroll
            for (int ks = 0; ks < 4; ++ks) {
                const int arow = abase[mt] + k;
                const int byte = (arow * 128 + ks * 32 + ioff) ^ ((arow & 7) << 4);
                afr[mt][k][ks] = *reinterpret_cast<const short8*>(Asm + byte);
            }

    // prefetch first caption's B into registers
    int4 breg[8];
    {
        const unsigned short* WG = Wp2L + ((size_t)(nq * 8) * 16 + g) * 12288;
        #pragma unroll
        for (int t = 0; t < 8; ++t)
            breg[t] = *reinterpret_cast<const int4*>(WG + (size_t)(tid + t * 192) * 8);
    }

    const float inv36 = 1.f / 36.f;
    for (int ni = 0; ni < 8; ++ni) {
        const int n = nq * 8 + ni;
        __syncthreads();   // sync1: prev MFMA reads done; Sw(prev) complete
        #pragma unroll
        for (int t = 0; t < 8; ++t)
            *reinterpret_cast<int4*>(Bsm + (size_t)(tid + t * 192) * 16) = breg[t];
        if (ni > 0 && tid < 128) {       // finish caption n-1 (waves 0,1)
            const int b = tid >> 4, j = tid & 15;
            float d = 0.f, ss = 0.f;
            #pragma unroll
            for (int u = 0; u < 4; ++u) {
                const int o = j * 4 + u;
                const float M = (Sw[0][b][o] + Sw[1][b][o] + Sw[2][b][o]) * inv36;
                Sw[0][b][o] = 0.f; Sw[1][b][o] = 0.f; Sw[2][b][o] = 0.f;
                const float ca  = cap_act [(n - 1) * LATENT + g * CPG + o];
                const float crv = cap_repr[(n - 1) * LATENT + g * CPG + o];
                const float tmp = M * ca;
                d = fmaf(tmp, crv, d);
                ss = fmaf(tmp, tmp, ss);
            }
            #pragma unroll
            for (int off = 1; off <= 8; off <<= 1) {
                d += __shfl_xor(d, off);
                ss += __shfl_xor(ss, off);
            }
            if (j == 0) {
                part_dot[((size_t)(n - 1) * BI + b0 + b) * NGROUPS + g] = d;
                part_ss [((size_t)(n - 1) * BI + b0 + b) * NGROUPS + g] = ss;
            }
        }
        __syncthreads();   // sync2: Bsm ready; Sw zeroed
        if (ni < 7) {      // issue next caption's loads (hidden under MFMA)
            const unsigned short* WG = Wp2L + ((size_t)(n + 1) * 16 + g) * 12288;
            #pragma unroll
            for (int t = 0; t < 8; ++t)
                breg[t] = *reinterpret_cast<const int4*>(WG + (size_t)(tid + t * 192) * 8);
        }

        f32x16 acc[3][2] = {};
        #pragma unroll
        for (int k = 0; k < 3; ++k) {
            #pragma unroll
            for (int ks = 0; ks < 4; ++ks) {
                const int brow0 = k * 64 + lrow;
                const int byte0 = (brow0 * 128 + ks * 32 + ioff) ^ ((brow0 & 7) << 4);
                const short8 bfr0 = *reinterpret_cast<const short8*>(Bsm + byte0);
                const int brow1 = k * 64 + 32 + lrow;
                const int byte1 = (brow1 * 128 + ks * 32 + ioff) ^ ((brow1 & 7) << 4);
                const short8 bfr1 = *reinterpret_cast<const short8*>(Bsm + byte1);
                #pragma unroll
                for (int mt = 0; mt < 3; ++mt) {
                    acc[mt][0] = __builtin_amdgcn_mfma_f32_32x32x16_bf16(afr[mt][k][ks], bfr0, acc[mt][0], 0, 0, 0);
                    acc[mt][1] = __builtin_amdgcn_mfma_f32_32x32x16_bf16(afr[mt][k][ks], bfr1, acc[mt][1], 0, 0, 0);
                }
            }
        }

        // epilogue: leaky + column sums -> Sw (shfl-combined, no atomics)
        #pragma unroll
        for (int mt = 0; mt < 3; ++mt) {
            const int rbase = wv * 96 + mt * 32;
            const int bfirst = rbase / 36;
            const int bsplit = (bfirst + 1) * 36 - rbase;
            #pragma unroll
            for (int nt = 0; nt < 2; ++nt) {
                float sA = 0.f, sB = 0.f;
                #pragma unroll
                for (int reg = 0; reg < 16; ++reg) {
                    const int rit = (reg & 3) + 8 * (reg >> 2) + 4 * khalf;
                    const float v = leakyf(acc[mt][nt][reg]);
                    if (rit >= bsplit) sB += v; else sA += v;
                }
                sA += __shfl_xor(sA, 32);
                sB += __shfl_xor(sB, 32);
                if (khalf == 0) {
                    const int o = nt * 32 + lrow;
                    Sw[wv][bfirst][o] += sA;
                    if (bsplit < 32) Sw[wv][bfirst + 1][o] += sB;
                }
            }
        }
    }
    __syncthreads();
    if (tid < 128) {       // finish last caption
        const int nlast = nq * 8 + 7;
        const int b = tid >> 4, j = tid & 15;
        float d = 0.f, ss = 0.f;
        #pragma unroll
        for (int u = 0; u < 4; ++u) {
            const int o = j * 4 + u;
            const float M = (Sw[0][b][o] + Sw[1][b][o] + Sw[2][b][o]) * inv36;
            const float ca  = cap_act [nlast * LATENT + g * CPG + o];
            const float crv = cap_repr[nlast * LATENT + g * CPG + o];
            const float tmp = M * ca;
            d = fmaf(tmp, crv, d);
            ss = fmaf(tmp, tmp, ss);
        }
        #pragma unroll
        for (int off = 1; off <= 8; off <<= 1) {
            d += __shfl_xor(d, off);
            ss += __shfl_xor(ss, off);
        }
        if (j == 0) {
            part_dot[((size_t)nlast * BI + b0 + b) * NGROUPS + g] = d;
            part_ss [((size_t)nlast * BI + b0 + b) * NGROUPS + g] = ss;
        }
    }
}

// ---------------------------------------------------------------------------
// Kernel 5: combine 16 group-partials -> sims[b*32+n]
// ---------------------------------------------------------------------------
__global__ __launch_bounds__(256) void final_kernel(
    const float* __restrict__ part_dot, const float* __restrict__ part_ss,
    const float* __restrict__ norm_capr, float* __restrict__ out)
{
    const int idx = blockIdx.x * 256 + threadIdx.x;   // 4096
    const int n = idx & 31;
    const int b = idx >> 5;
    const size_t base = ((size_t)n * BI + b) * NGROUPS;
    float d = 0.f, s = 0.f;
    #pragma unroll
    for (int g = 0; g < NGROUPS; ++g) { d += part_dot[base + g]; s += part_ss[base + g]; }
    out[b * BC + n] = d / (sqrtf(s) * norm_capr[n]);
}

// ---------------------------------------------------------------------------
extern "C" void kernel_launch(void* const* d_in, const int* in_sizes, int n_in,
                              void* d_out, int out_size, void* d_ws, size_t ws_size,
                              hipStream_t stream) {
    const float* img_embed = (const float*)d_in[0];   // (128, 36, 1024)
    const float* cap_embed = (const float*)d_in[1];   // (32, 50, 1024)
    const int*   lens      = (const int*)  d_in[2];   // (32,)
    const float* red_w     = (const float*)d_in[3];   // (1024, 256)
    const float* red_b     = (const float*)d_in[4];   // (256,)
    const float* proj_w    = (const float*)d_in[5];   // (256, 196608)
    const float* proj_b    = (const float*)d_in[6];   // (196608,)
    float* out = (float*)d_out;                        // (128, 32)

    char* ws = (char*)d_ws;
    unsigned short* Wp2L   = (unsigned short*)(ws);                    // 12,582,912 B
    unsigned short* img_bf = (unsigned short*)(ws + 12582912);         //  9,437,184 B
    float* cap_repr  = (float*)(ws + 22020096);                        //    131,072 B
    float* cap_act   = (float*)(ws + 22151168);                        //    131,072 B
    float* qT        = (float*)(ws + 22282240);                        //     32,768 B
    float* norm_capr = (float*)(ws + 22315008);                        //        512 B
    float* part_dot  = (float*)(ws + 22315520);                        //    262,144 B
    float* part_ss   = (float*)(ws + 22577664);                        //    262,144 B

    hipLaunchKernelGGL(cap_mean_kernel, dim3(BC), dim3(256), 0, stream,
                       cap_embed, lens, cap_repr, cap_act, norm_capr);
    hipLaunchKernelGGL(q_kernel, dim3(8, BC), dim3(256), 0, stream,
                       cap_repr, red_w, red_b, qT);
    hipLaunchKernelGGL(img2bf_kernel, dim3(2304), dim3(256), 0, stream,
                       img_embed, img_bf);
    hipLaunchKernelGGL(wgen4_kernel, dim3(1024), dim3(192), 0, stream,
                       qT, proj_w, proj_b, Wp2L);
    hipLaunchKernelGGL(conv3_kernel, dim3(NGROUPS, 16, 4), dim3(192), 0, stream,
                       img_bf, Wp2L, cap_repr, cap_act, part_dot, part_ss);
    hipLaunchKernelGGL(final_kernel, dim3(16), dim3(256), 0, stream,
                       part_dot, part_ss, norm_capr, out);
}

// Round 5
// 245.345 us; speedup vs baseline: 1.2795x; 1.2795x over previous
//
#include <hip/hip_runtime.h>
#include <math.h>

#define LATENT 1024
#define QDIM 256
#define NW 196608           // LATENT * CPG * K
#define BI 128
#define BC 32
#define TT 50
#define REGIONS 36
#define NGROUPS 16
#define CPG 64
#define NEG 0.1f

typedef __attribute__((ext_vector_type(8))) short short8;
typedef __attribute__((ext_vector_type(16))) float f32x16;

__device__ __forceinline__ float leakyf(float x){ return x > 0.f ? x : NEG * x; }

__device__ __forceinline__ unsigned short f2bf(float x){
    union { float f; unsigned int u; } v; v.f = x;
    unsigned int r = v.u + 0x7FFFu + ((v.u >> 16) & 1u);   // RNE
    return (unsigned short)(r >> 16);
}

// ---------------------------------------------------------------------------
// Kernel 1a: masked mean + gate(pre-scaled by 1/36) + ||cap_repr||.
// ---------------------------------------------------------------------------
__global__ __launch_bounds__(256) void cap_mean_kernel(
    const float* __restrict__ cap_embed, const int* __restrict__ lens,
    float* __restrict__ cap_repr, float* __restrict__ cap_act,
    float* __restrict__ norm_capr)
{
    const int n = blockIdx.x;
    const int len = lens[n];
    const float invl = 1.f / (float)len;
    const int c4 = threadIdx.x;            // 4 channels per thread
    const float* base = cap_embed + (size_t)n * TT * LATENT + c4 * 4;
    float4 s = {0.f, 0.f, 0.f, 0.f};
    for (int t = 0; t < len; ++t) {
        const float4 v = *reinterpret_cast<const float4*>(base + (size_t)t * LATENT);
        s.x += v.x; s.y += v.y; s.z += v.z; s.w += v.w;
    }
    float4 m = {s.x * invl, s.y * invl, s.z * invl, s.w * invl};
    *reinterpret_cast<float4*>(cap_repr + n * LATENT + c4 * 4) = m;
    const float sc = 1.f / 36.f;           // fold conv's mean(l) divisor
    float4 a = {leakyf(m.x) * sc, leakyf(m.y) * sc, leakyf(m.z) * sc, leakyf(m.w) * sc};
    *reinterpret_cast<float4*>(cap_act + n * LATENT + c4 * 4) = a;
    float ss = m.x*m.x + m.y*m.y + m.z*m.z + m.w*m.w;
    #pragma unroll
    for (int off = 32; off; off >>= 1) ss += __shfl_xor(ss, off);
    __shared__ float red4[4];
    if ((threadIdx.x & 63) == 0) red4[threadIdx.x >> 6] = ss;
    __syncthreads();
    if (threadIdx.x == 0) norm_capr[n] = sqrtf(red4[0] + red4[1] + red4[2] + red4[3]);
}

// ---------------------------------------------------------------------------
// Kernel 1b: qT[r][n] = cap_repr[n,:] @ red_w[:,r] + red_b[r]
// ---------------------------------------------------------------------------
__global__ __launch_bounds__(256) void q_kernel(
    const float* __restrict__ cap_repr, const float* __restrict__ red_w,
    const float* __restrict__ red_b, float* __restrict__ qT)
{
    const int cg = blockIdx.x, n = blockIdx.y;
    const int col = threadIdx.x & 31, ks = threadIdx.x >> 5;
    const float* cr = cap_repr + n * LATENT;
    float p = 0.f;
    const int r0 = ks * 128;
    for (int r = r0; r < r0 + 128; ++r)
        p = fmaf(cr[r], red_w[(size_t)r * QDIM + cg * 32 + col], p);
    __shared__ float part[256];
    part[threadIdx.x] = p;
    __syncthreads();
    if (threadIdx.x < 32) {
        float s = red_b[cg * 32 + col];
        #pragma unroll
        for (int k = 0; k < 8; ++k) s += part[k * 32 + col];
        qT[(cg * 32 + col) * 32 + n] = s;
    }
}

// ---------------------------------------------------------------------------
// Kernel 2: img f32 -> bf16 (same layout)
// ---------------------------------------------------------------------------
__global__ __launch_bounds__(256) void img2bf_kernel(
    const float* __restrict__ in, unsigned short* __restrict__ out)
{
    const size_t base = ((size_t)blockIdx.x * 256 + threadIdx.x) * 8;
    const float4 u = *reinterpret_cast<const float4*>(in + base);
    const float4 v = *reinterpret_cast<const float4*>(in + base + 4);
    unsigned short r[8];
    r[0]=f2bf(u.x); r[1]=f2bf(u.y); r[2]=f2bf(u.z); r[3]=f2bf(u.w);
    r[4]=f2bf(v.x); r[5]=f2bf(v.y); r[6]=f2bf(v.z); r[7]=f2bf(v.w);
    *reinterpret_cast<int4*>(out + base) = *reinterpret_cast<const int4*>(r);
}

// ---------------------------------------------------------------------------
// Kernel 3: wgen5 — 2 cols/thread, 192 thr, 512 blocks (384 cols each).
// q rows read via wave-uniform s_loads; epilogue: softmax(K=3) + bf16 pack
// into FRAG-MAJOR Wp2F: per (n,g): frag(k,nt,ks)*512 + (khalf*32+lrow)*8 + j
//   where nt=o>>5, lrow=o&31, ks=i>>4, khalf=(i>>3)&1, j=i&7.
// ---------------------------------------------------------------------------
__global__ __launch_bounds__(192) void wgen5_kernel(
    const float* __restrict__ qT, const float* __restrict__ proj_w,
    const float* __restrict__ proj_b, unsigned short* __restrict__ Wp2F)
{
    __shared__ float L[384 * 33];
    const int tid = threadIdx.x;
    const int col0 = blockIdx.x * 384 + tid;
    const int col1 = col0 + 192;
    float acc0[32], acc1[32];
    #pragma unroll
    for (int n2 = 0; n2 < 32; ++n2) { acc0[n2] = 0.f; acc1[n2] = 0.f; }
    const float* pw = proj_w;
    #pragma unroll 2
    for (int r = 0; r < QDIM; ++r) {
        const float w0 = pw[(size_t)r * NW + col0];
        const float w1 = pw[(size_t)r * NW + col1];
        const float* qr = qT + r * 32;     // uniform address -> s_load
        #pragma unroll
        for (int nb = 0; nb < 8; ++nb) {
            const float4 qv = *reinterpret_cast<const float4*>(qr + nb * 4);
            acc0[nb*4+0] = fmaf(w0, qv.x, acc0[nb*4+0]);
            acc0[nb*4+1] = fmaf(w0, qv.y, acc0[nb*4+1]);
            acc0[nb*4+2] = fmaf(w0, qv.z, acc0[nb*4+2]);
            acc0[nb*4+3] = fmaf(w0, qv.w, acc0[nb*4+3]);
            acc1[nb*4+0] = fmaf(w1, qv.x, acc1[nb*4+0]);
            acc1[nb*4+1] = fmaf(w1, qv.y, acc1[nb*4+1]);
            acc1[nb*4+2] = fmaf(w1, qv.z, acc1[nb*4+2]);
            acc1[nb*4+3] = fmaf(w1, qv.w, acc1[nb*4+3]);
        }
    }
    const float b0 = proj_b[col0], b1 = proj_b[col1];
    #pragma unroll
    for (int n2 = 0; n2 < 32; ++n2) {
        L[tid * 33 + n2]         = acc0[n2] + b0;
        L[(tid + 192) * 33 + n2] = acc1[n2] + b1;
    }
    __syncthreads();
    const int g = blockIdx.x >> 5;               // 32 blocks per group
    const int opair = blockIdx.x & 31;           // block covers o = 2*opair, 2*opair+1
    for (int idx = tid; idx < 4096; idx += 192) {
        const int n = idx & 31, tl = idx >> 5;   // tl < 128
        const int oloc = tl >> 6, i = tl & 63;
        const int c = oloc * 192 + i * 3;
        const float x0 = L[c * 33 + n], x1 = L[(c+1)*33 + n], x2 = L[(c+2)*33 + n];
        const float m = fmaxf(fmaxf(x0, x1), x2);
        const float e0 = expf(x0 - m), e1 = expf(x1 - m), e2 = expf(x2 - m);
        const float inv = 1.f / (e0 + e1 + e2);
        const int o = opair * 2 + oloc;
        const int nt = o >> 5, lrow = o & 31;
        const int ks = i >> 4, khalf = (i >> 3) & 1, j = i & 7;
        const size_t base = (size_t)(n * 16 + g) * 12288
                          + (size_t)(((0 * 2 + nt) * 4 + ks)) * 512
                          + khalf * 256 + lrow * 8 + j;
        // k strides by 8 frags = 4096 elements in frag index space
        Wp2F[base]        = f2bf(e0 * inv);
        Wp2F[base + 4096] = f2bf(e1 * inv);
        Wp2F[base + 8192] = f2bf(e2 * inv);
    }
}

// ---------------------------------------------------------------------------
// Kernel 4: conv4 — A staged in LDS (swizzled) once per 16 captions;
// B-frags read DIRECTLY from global frag-major Wp2F (no LDS for B);
// no-atomic epilogue via per-wave Sw slices. 192 thr = 3 waves.
// grid = (g=16, bt=16, nq=2), 16 captions inner.
// ---------------------------------------------------------------------------
__global__ __launch_bounds__(192, 2) void conv4_kernel(
    const unsigned short* __restrict__ img_bf, const unsigned short* __restrict__ Wp2F,
    const float* __restrict__ cap_repr, const float* __restrict__ cap_act,
    float* __restrict__ part_dot, float* __restrict__ part_ss)
{
    const int g = blockIdx.x, bt = blockIdx.y, nq = blockIdx.z;
    const int b0 = bt * 8;
    __shared__ char Asm[8 * 38 * 128];   // [row=b*38+pos][64 bf16], swizzled
    __shared__ float Sw[3][8][64];       // per-wave partial sums
    const int tid = threadIdx.x;
    const int wv = tid >> 6, lane = tid & 63;
    const int lrow = lane & 31, khalf = lane >> 5;
    const int ioff = khalf * 16;

    for (int idx = tid; idx < 1536; idx += 192) ((float*)Sw)[idx] = 0.f;

    // stage A once (reused for 16 captions)
    const unsigned short* imgG = img_bf + (size_t)b0 * 36 * 1024 + g * 64;
    for (int idx = tid; idx < 2304; idx += 192) {
        const int row_img = idx >> 3, ch = idx & 7;
        const int bb = row_img / 36;
        const int l = row_img - bb * 36;
        const int4 v = *reinterpret_cast<const int4*>(imgG + (size_t)row_img * 1024 + ch * 8);
        const int arow = bb * 38 + l + 1;
        const int byte = (arow * 128 + ch * 16) ^ ((arow & 7) << 4);
        *reinterpret_cast<int4*>(Asm + byte) = v;
    }
    for (int idx = tid; idx < 128; idx += 192) {   // zero pad rows
        const int r = idx >> 3, ch = idx & 7;
        const int arow = (r >> 1) * 38 + (r & 1) * 37;
        const int byte = (arow * 128 + ch * 16) ^ ((arow & 7) << 4);
        int4 z; z.x = 0; z.y = 0; z.z = 0; z.w = 0;
        *reinterpret_cast<int4*>(Asm + byte) = z;
    }
    __syncthreads();

    int abase[3];
    #pragma unroll
    for (int mt = 0; mt < 3; ++mt) {
        const int r = wv * 96 + mt * 32 + lrow;
        const int bb = r / 36;
        abase[mt] = bb * 38 + (r - bb * 36);
    }

    for (int ni = 0; ni < 16; ++ni) {
        const int n = nq * 16 + ni;
        const unsigned short* WF = Wp2F + (size_t)(n * 16 + g) * 12288 + (size_t)lane * 8;

        f32x16 acc[3][2] = {};
        #pragma unroll
        for (int k = 0; k < 3; ++k) {
            #pragma unroll
            for (int ks = 0; ks < 4; ++ks) {
                const short8 bf0 = *reinterpret_cast<const short8*>(WF + (k * 8 + ks) * 512);
                const short8 bf1 = *reinterpret_cast<const short8*>(WF + (k * 8 + 4 + ks) * 512);
                #pragma unroll
                for (int mt = 0; mt < 3; ++mt) {
                    const int arow = abase[mt] + k;
                    const int byte = (arow * 128 + ks * 32 + ioff) ^ ((arow & 7) << 4);
                    const short8 af = *reinterpret_cast<const short8*>(Asm + byte);
                    acc[mt][0] = __builtin_amdgcn_mfma_f32_32x32x16_bf16(af, bf0, acc[mt][0], 0, 0, 0);
                    acc[mt][1] = __builtin_amdgcn_mfma_f32_32x32x16_bf16(af, bf1, acc[mt][1], 0, 0, 0);
                }
            }
        }

        // leaky + column sums -> Sw (C/D: col=lane&31, row=(reg&3)+8*(reg>>2)+4*khalf)
        #pragma unroll
        for (int mt = 0; mt < 3; ++mt) {
            const int rbase = wv * 96 + mt * 32;
            const int bfirst = rbase / 36;
            const int bsplit = (bfirst + 1) * 36 - rbase;
            #pragma unroll
            for (int nt = 0; nt < 2; ++nt) {
                float sA = 0.f, sB = 0.f;
                #pragma unroll
                for (int reg = 0; reg < 16; ++reg) {
                    const int rit = (reg & 3) + 8 * (reg >> 2) + 4 * khalf;
                    const float v = leakyf(acc[mt][nt][reg]);
                    if (rit >= bsplit) sB += v; else sA += v;
                }
                sA += __shfl_xor(sA, 32);
                sB += __shfl_xor(sB, 32);
                if (khalf == 0) {
                    const int o = nt * 32 + lrow;
                    Sw[wv][bfirst][o] += sA;
                    if (bsplit < 32) Sw[wv][bfirst + 1][o] += sB;
                }
            }
        }
        __syncthreads();   // Sw complete

        if (tid < 128) {   // finish caption n (waves 0,1), zero Sw for next
            const int b = tid >> 4, j = tid & 15;
            const float4 ca4 = *reinterpret_cast<const float4*>(&cap_act [n * LATENT + g * CPG + j * 4]);
            const float4 cr4 = *reinterpret_cast<const float4*>(&cap_repr[n * LATENT + g * CPG + j * 4]);
            float d = 0.f, ss = 0.f;
            const float cav[4] = {ca4.x, ca4.y, ca4.z, ca4.w};
            const float crv[4] = {cr4.x, cr4.y, cr4.z, cr4.w};
            #pragma unroll
            for (int u = 0; u < 4; ++u) {
                const int o = j * 4 + u;
                const float S = Sw[0][b][o] + Sw[1][b][o] + Sw[2][b][o];
                Sw[0][b][o] = 0.f; Sw[1][b][o] = 0.f; Sw[2][b][o] = 0.f;
                const float tmp = S * cav[u];          // cap_act pre-scaled by 1/36
                d = fmaf(tmp, crv[u], d);
                ss = fmaf(tmp, tmp, ss);
            }
            #pragma unroll
            for (int off = 1; off <= 8; off <<= 1) {
                d += __shfl_xor(d, off);
                ss += __shfl_xor(ss, off);
            }
            if (j == 0) {
                part_dot[((size_t)n * BI + b0 + b) * NGROUPS + g] = d;
                part_ss [((size_t)n * BI + b0 + b) * NGROUPS + g] = ss;
            }
        }
        __syncthreads();   // Sw zeroed before next caption accumulates
    }
}

// ---------------------------------------------------------------------------
// Kernel 5: combine 16 group-partials -> sims[b*32+n]
// ---------------------------------------------------------------------------
__global__ __launch_bounds__(256) void final_kernel(
    const float* __restrict__ part_dot, const float* __restrict__ part_ss,
    const float* __restrict__ norm_capr, float* __restrict__ out)
{
    const int idx = blockIdx.x * 256 + threadIdx.x;   // 4096
    const int n = idx & 31;
    const int b = idx >> 5;
    const size_t base = ((size_t)n * BI + b) * NGROUPS;
    float d = 0.f, s = 0.f;
    #pragma unroll
    for (int g = 0; g < NGROUPS; ++g) { d += part_dot[base + g]; s += part_ss[base + g]; }
    out[b * BC + n] = d / (sqrtf(s) * norm_capr[n]);
}

// ---------------------------------------------------------------------------
extern "C" void kernel_launch(void* const* d_in, const int* in_sizes, int n_in,
                              void* d_out, int out_size, void* d_ws, size_t ws_size,
                              hipStream_t stream) {
    const float* img_embed = (const float*)d_in[0];   // (128, 36, 1024)
    const float* cap_embed = (const float*)d_in[1];   // (32, 50, 1024)
    const int*   lens      = (const int*)  d_in[2];   // (32,)
    const float* red_w     = (const float*)d_in[3];   // (1024, 256)
    const float* red_b     = (const float*)d_in[4];   // (256,)
    const float* proj_w    = (const float*)d_in[5];   // (256, 196608)
    const float* proj_b    = (const float*)d_in[6];   // (196608,)
    float* out = (float*)d_out;                        // (128, 32)

    char* ws = (char*)d_ws;
    unsigned short* Wp2F   = (unsigned short*)(ws);                    // 12,582,912 B
    unsigned short* img_bf = (unsigned short*)(ws + 12582912);         //  9,437,184 B
    float* cap_repr  = (float*)(ws + 22020096);                        //    131,072 B
    float* cap_act   = (float*)(ws + 22151168);                        //    131,072 B
    float* qT        = (float*)(ws + 22282240);                        //     32,768 B
    float* norm_capr = (float*)(ws + 22315008);                        //        512 B
    float* part_dot  = (float*)(ws + 22315520);                        //    262,144 B
    float* part_ss   = (float*)(ws + 22577664);                        //    262,144 B

    hipLaunchKernelGGL(cap_mean_kernel, dim3(BC), dim3(256), 0, stream,
                       cap_embed, lens, cap_repr, cap_act, norm_capr);
    hipLaunchKernelGGL(q_kernel, dim3(8, BC), dim3(256), 0, stream,
                       cap_repr, red_w, red_b, qT);
    hipLaunchKernelGGL(img2bf_kernel, dim3(2304), dim3(256), 0, stream,
                       img_embed, img_bf);
    hipLaunchKernelGGL(wgen5_kernel, dim3(512), dim3(192), 0, stream,
                       qT, proj_w, proj_b, Wp2F);
    hipLaunchKernelGGL(conv4_kernel, dim3(NGROUPS, 16, 2), dim3(192), 0, stream,
                       img_bf, Wp2F, cap_repr, cap_act, part_dot, part_ss);
    hipLaunchKernelGGL(final_kernel, dim3(16), dim3(256), 0, stream,
                       part_dot, part_ss, norm_capr, out);
}

// Round 6
// 221.959 us; speedup vs baseline: 1.4143x; 1.1054x over previous
//
#include <hip/hip_runtime.h>
#include <math.h>

#define LATENT 1024
#define QDIM 256
#define NW 196608           // LATENT * CPG * K
#define BI 128
#define BC 32
#define TT 50
#define REGIONS 36
#define NGROUPS 16
#define CPG 64
#define NEG 0.1f

typedef __attribute__((ext_vector_type(8))) short short8;
typedef __attribute__((ext_vector_type(16))) float f32x16;

__device__ __forceinline__ float leakyf(float x){ return x > 0.f ? x : NEG * x; }

__device__ __forceinline__ unsigned short f2bf(float x){
    union { float f; unsigned int u; } v; v.f = x;
    unsigned int r = v.u + 0x7FFFu + ((v.u >> 16) & 1u);   // RNE
    return (unsigned short)(r >> 16);
}

// ---------------------------------------------------------------------------
// Kernel 1a: masked mean + gate(pre-scaled by 1/36) + ||cap_repr||.
// ---------------------------------------------------------------------------
__global__ __launch_bounds__(256) void cap_mean_kernel(
    const float* __restrict__ cap_embed, const int* __restrict__ lens,
    float* __restrict__ cap_repr, float* __restrict__ cap_act,
    float* __restrict__ norm_capr)
{
    const int n = blockIdx.x;
    const int len = lens[n];
    const float invl = 1.f / (float)len;
    const int c4 = threadIdx.x;            // 4 channels per thread
    const float* base = cap_embed + (size_t)n * TT * LATENT + c4 * 4;
    float4 s = {0.f, 0.f, 0.f, 0.f};
    for (int t = 0; t < len; ++t) {
        const float4 v = *reinterpret_cast<const float4*>(base + (size_t)t * LATENT);
        s.x += v.x; s.y += v.y; s.z += v.z; s.w += v.w;
    }
    float4 m = {s.x * invl, s.y * invl, s.z * invl, s.w * invl};
    *reinterpret_cast<float4*>(cap_repr + n * LATENT + c4 * 4) = m;
    const float sc = 1.f / 36.f;           // fold conv's mean(l) divisor
    float4 a = {leakyf(m.x) * sc, leakyf(m.y) * sc, leakyf(m.z) * sc, leakyf(m.w) * sc};
    *reinterpret_cast<float4*>(cap_act + n * LATENT + c4 * 4) = a;
    float ss = m.x*m.x + m.y*m.y + m.z*m.z + m.w*m.w;
    #pragma unroll
    for (int off = 32; off; off >>= 1) ss += __shfl_xor(ss, off);
    __shared__ float red4[4];
    if ((threadIdx.x & 63) == 0) red4[threadIdx.x >> 6] = ss;
    __syncthreads();
    if (threadIdx.x == 0) norm_capr[n] = sqrtf(red4[0] + red4[1] + red4[2] + red4[3]);
}

// ---------------------------------------------------------------------------
// Kernel 1b: qT[r][n] = cap_repr[n,:] @ red_w[:,r] + red_b[r]
// ---------------------------------------------------------------------------
__global__ __launch_bounds__(256) void q_kernel(
    const float* __restrict__ cap_repr, const float* __restrict__ red_w,
    const float* __restrict__ red_b, float* __restrict__ qT)
{
    const int cg = blockIdx.x, n = blockIdx.y;
    const int col = threadIdx.x & 31, ks = threadIdx.x >> 5;
    const float* cr = cap_repr + n * LATENT;
    float p = 0.f;
    const int r0 = ks * 128;
    for (int r = r0; r < r0 + 128; ++r)
        p = fmaf(cr[r], red_w[(size_t)r * QDIM + cg * 32 + col], p);
    __shared__ float part[256];
    part[threadIdx.x] = p;
    __syncthreads();
    if (threadIdx.x < 32) {
        float s = red_b[cg * 32 + col];
        #pragma unroll
        for (int k = 0; k < 8; ++k) s += part[k * 32 + col];
        qT[(cg * 32 + col) * 32 + n] = s;
    }
}

// ---------------------------------------------------------------------------
// Kernel 2: wgen6 — 1 col/thread, 1024 blocks x 192 thr (block = one (g,o)).
// 12 waves/CU. q rows via wave-uniform s_loads; K-loop unrolled 4 for MLP.
// Epilogue: softmax(K=3) + bf16 pack into frag-major Wp2F.
// ---------------------------------------------------------------------------
__global__ __launch_bounds__(192) void wgen6_kernel(
    const float* __restrict__ qT, const float* __restrict__ proj_w,
    const float* __restrict__ proj_b, unsigned short* __restrict__ Wp2F)
{
    __shared__ float L[192 * 33];
    const int tid = threadIdx.x;
    const int g = blockIdx.x >> 6, o = blockIdx.x & 63;
    const int col = (g * 64 + o) * 192 + tid;
    float acc[32];
    #pragma unroll
    for (int n2 = 0; n2 < 32; ++n2) acc[n2] = 0.f;
    #pragma unroll 4
    for (int r = 0; r < QDIM; ++r) {
        const float w = proj_w[(size_t)r * NW + col];
        const float* qr = qT + r * 32;     // uniform address -> s_load
        #pragma unroll
        for (int nb = 0; nb < 8; ++nb) {
            const float4 qv = *reinterpret_cast<const float4*>(qr + nb * 4);
            acc[nb*4+0] = fmaf(w, qv.x, acc[nb*4+0]);
            acc[nb*4+1] = fmaf(w, qv.y, acc[nb*4+1]);
            acc[nb*4+2] = fmaf(w, qv.z, acc[nb*4+2]);
            acc[nb*4+3] = fmaf(w, qv.w, acc[nb*4+3]);
        }
    }
    const float b = proj_b[col];
    #pragma unroll
    for (int n2 = 0; n2 < 32; ++n2) L[tid * 33 + n2] = acc[n2] + b;
    __syncthreads();
    const int nt = o >> 5, lrow = o & 31;
    for (int idx = tid; idx < 2048; idx += 192) {
        const int n = idx & 31, i = idx >> 5;      // i < 64
        const int c = i * 3;
        const float x0 = L[c * 33 + n], x1 = L[(c+1)*33 + n], x2 = L[(c+2)*33 + n];
        const float m = fmaxf(fmaxf(x0, x1), x2);
        const float e0 = expf(x0 - m), e1 = expf(x1 - m), e2 = expf(x2 - m);
        const float inv = 1.f / (e0 + e1 + e2);
        const int ks = i >> 4, khalf = (i >> 3) & 1, j = i & 7;
        const size_t base = (size_t)(n * 16 + g) * 12288
                          + (size_t)(nt * 4 + ks) * 512
                          + khalf * 256 + lrow * 8 + j;
        Wp2F[base]        = f2bf(e0 * inv);   // k=0
        Wp2F[base + 4096] = f2bf(e1 * inv);   // k=1 (+8 frags)
        Wp2F[base + 8192] = f2bf(e2 * inv);   // k=2
    }
}

// ---------------------------------------------------------------------------
// Kernel 3: conv4b — A staged from f32 img directly (fused convert) once per
// 16 captions; B-frags from global frag-major Wp2F with P/Q register
// prefetch (P: k=0 frags loaded during prev epilogue; Q: k=1,2 frags issued
// before k=0 MFMA). No-atomic epilogue. 192 thr = 3 waves, 2 blocks/CU.
// grid = (g=16, bt=16, nq=2).
// ---------------------------------------------------------------------------
__global__ __launch_bounds__(192, 2) void conv4b_kernel(
    const float* __restrict__ img_embed, const unsigned short* __restrict__ Wp2F,
    const float* __restrict__ cap_repr, const float* __restrict__ cap_act,
    float* __restrict__ part_dot, float* __restrict__ part_ss)
{
    const int g = blockIdx.x, bt = blockIdx.y, nq = blockIdx.z;
    const int b0 = bt * 8;
    __shared__ char Asm[8 * 38 * 128];   // [row=b*38+pos][64 bf16], swizzled
    __shared__ float Sw[3][8][64];       // per-wave partial sums
    const int tid = threadIdx.x;
    const int wv = tid >> 6, lane = tid & 63;
    const int lrow = lane & 31, khalf = lane >> 5;
    const int ioff = khalf * 16;

    for (int idx = tid; idx < 1536; idx += 192) ((float*)Sw)[idx] = 0.f;

    // stage A once (fused f32->bf16 convert), reused for 16 captions
    const float* imgG = img_embed + (size_t)b0 * 36 * 1024 + g * 64;
    for (int idx = tid; idx < 2304; idx += 192) {
        const int row_img = idx >> 3, ch = idx & 7;
        const int bb = row_img / 36;
        const int l = row_img - bb * 36;
        const float* src = imgG + (size_t)row_img * 1024 + ch * 8;
        const float4 u = *reinterpret_cast<const float4*>(src);
        const float4 v = *reinterpret_cast<const float4*>(src + 4);
        unsigned short r8[8];
        r8[0]=f2bf(u.x); r8[1]=f2bf(u.y); r8[2]=f2bf(u.z); r8[3]=f2bf(u.w);
        r8[4]=f2bf(v.x); r8[5]=f2bf(v.y); r8[6]=f2bf(v.z); r8[7]=f2bf(v.w);
        const int arow = bb * 38 + l + 1;
        const int byte = (arow * 128 + ch * 16) ^ ((arow & 7) << 4);
        *reinterpret_cast<int4*>(Asm + byte) = *reinterpret_cast<const int4*>(r8);
    }
    for (int idx = tid; idx < 128; idx += 192) {   // zero pad rows
        const int r = idx >> 3, ch = idx & 7;
        const int arow = (r >> 1) * 38 + (r & 1) * 37;
        const int byte = (arow * 128 + ch * 16) ^ ((arow & 7) << 4);
        int4 z; z.x = 0; z.y = 0; z.z = 0; z.w = 0;
        *reinterpret_cast<int4*>(Asm + byte) = z;
    }

    int abase[3];
    #pragma unroll
    for (int mt = 0; mt < 3; ++mt) {
        const int r = wv * 96 + mt * 32 + lrow;
        const int bb = r / 36;
        abase[mt] = bb * 38 + (r - bb * 36);
    }

    // prefetch P = frags 0..7 (k=0) of first caption
    int4 P[8];
    {
        const unsigned short* WF0 = Wp2F + (size_t)((nq * 16) * 16 + g) * 12288 + (size_t)lane * 8;
        #pragma unroll
        for (int t = 0; t < 8; ++t)
            P[t] = *reinterpret_cast<const int4*>(WF0 + t * 512);
    }
    __syncthreads();   // Asm ready

    for (int ni = 0; ni < 16; ++ni) {
        const int n = nq * 16 + ni;
        const unsigned short* WF = Wp2F + (size_t)(n * 16 + g) * 12288 + (size_t)lane * 8;

        // issue Q = frags 8..23 (k=1,2); first needed after k=0's 24 MFMAs
        int4 Q[16];
        #pragma unroll
        for (int t = 0; t < 16; ++t)
            Q[t] = *reinterpret_cast<const int4*>(WF + (8 + t) * 512);

        f32x16 acc[3][2] = {};
        #pragma unroll
        for (int k = 0; k < 3; ++k) {
            #pragma unroll
            for (int ks = 0; ks < 4; ++ks) {
                short8 bf0, bf1;
                if (k == 0) {
                    bf0 = *reinterpret_cast<const short8*>(&P[ks]);
                    bf1 = *reinterpret_cast<const short8*>(&P[4 + ks]);
                } else if (k == 1) {
                    bf0 = *reinterpret_cast<const short8*>(&Q[ks]);
                    bf1 = *reinterpret_cast<const short8*>(&Q[4 + ks]);
                } else {
                    bf0 = *reinterpret_cast<const short8*>(&Q[8 + ks]);
                    bf1 = *reinterpret_cast<const short8*>(&Q[12 + ks]);
                }
                #pragma unroll
                for (int mt = 0; mt < 3; ++mt) {
                    const int arow = abase[mt] + k;
                    const int byte = (arow * 128 + ks * 32 + ioff) ^ ((arow & 7) << 4);
                    const short8 af = *reinterpret_cast<const short8*>(Asm + byte);
                    acc[mt][0] = __builtin_amdgcn_mfma_f32_32x32x16_bf16(af, bf0, acc[mt][0], 0, 0, 0);
                    acc[mt][1] = __builtin_amdgcn_mfma_f32_32x32x16_bf16(af, bf1, acc[mt][1], 0, 0, 0);
                }
            }
        }

        // prefetch P for caption n+1 (hidden under epilogue)
        if (ni < 15) {
            const unsigned short* WFn = Wp2F + (size_t)((n + 1) * 16 + g) * 12288 + (size_t)lane * 8;
            #pragma unroll
            for (int t = 0; t < 8; ++t)
                P[t] = *reinterpret_cast<const int4*>(WFn + t * 512);
        }

        // leaky + column sums -> Sw (C/D: col=lane&31, row=(reg&3)+8*(reg>>2)+4*khalf)
        #pragma unroll
        for (int mt = 0; mt < 3; ++mt) {
            const int rbase = wv * 96 + mt * 32;
            const int bfirst = rbase / 36;
            const int bsplit = (bfirst + 1) * 36 - rbase;
            #pragma unroll
            for (int nt = 0; nt < 2; ++nt) {
                float sA = 0.f, sB = 0.f;
                #pragma unroll
                for (int reg = 0; reg < 16; ++reg) {
                    const int rit = (reg & 3) + 8 * (reg >> 2) + 4 * khalf;
                    const float v = leakyf(acc[mt][nt][reg]);
                    if (rit >= bsplit) sB += v; else sA += v;
                }
                sA += __shfl_xor(sA, 32);
                sB += __shfl_xor(sB, 32);
                if (khalf == 0) {
                    const int o = nt * 32 + lrow;
                    Sw[wv][bfirst][o] += sA;
                    if (bsplit < 32) Sw[wv][bfirst + 1][o] += sB;
                }
            }
        }
        __syncthreads();   // Sw complete

        if (tid < 128) {   // finish caption n (waves 0,1), zero Sw for next
            const int b = tid >> 4, j = tid & 15;
            const float4 ca4 = *reinterpret_cast<const float4*>(&cap_act [n * LATENT + g * CPG + j * 4]);
            const float4 cr4 = *reinterpret_cast<const float4*>(&cap_repr[n * LATENT + g * CPG + j * 4]);
            float d = 0.f, ss = 0.f;
            const float cav[4] = {ca4.x, ca4.y, ca4.z, ca4.w};
            const float crv[4] = {cr4.x, cr4.y, cr4.z, cr4.w};
            #pragma unroll
            for (int u = 0; u < 4; ++u) {
                const int o = j * 4 + u;
                const float S = Sw[0][b][o] + Sw[1][b][o] + Sw[2][b][o];
                Sw[0][b][o] = 0.f; Sw[1][b][o] = 0.f; Sw[2][b][o] = 0.f;
                const float tmp = S * cav[u];          // cap_act pre-scaled by 1/36
                d = fmaf(tmp, crv[u], d);
                ss = fmaf(tmp, tmp, ss);
            }
            #pragma unroll
            for (int off = 1; off <= 8; off <<= 1) {
                d += __shfl_xor(d, off);
                ss += __shfl_xor(ss, off);
            }
            if (j == 0) {
                part_dot[((size_t)n * BI + b0 + b) * NGROUPS + g] = d;
                part_ss [((size_t)n * BI + b0 + b) * NGROUPS + g] = ss;
            }
        }
        __syncthreads();   // Sw zeroed before next caption accumulates
    }
}

// ---------------------------------------------------------------------------
// Kernel 4: combine 16 group-partials -> sims[b*32+n]
// ---------------------------------------------------------------------------
__global__ __launch_bounds__(256) void final_kernel(
    const float* __restrict__ part_dot, const float* __restrict__ part_ss,
    const float* __restrict__ norm_capr, float* __restrict__ out)
{
    const int idx = blockIdx.x * 256 + threadIdx.x;   // 4096
    const int n = idx & 31;
    const int b = idx >> 5;
    const size_t base = ((size_t)n * BI + b) * NGROUPS;
    float d = 0.f, s = 0.f;
    #pragma unroll
    for (int g = 0; g < NGROUPS; ++g) { d += part_dot[base + g]; s += part_ss[base + g]; }
    out[b * BC + n] = d / (sqrtf(s) * norm_capr[n]);
}

// ---------------------------------------------------------------------------
extern "C" void kernel_launch(void* const* d_in, const int* in_sizes, int n_in,
                              void* d_out, int out_size, void* d_ws, size_t ws_size,
                              hipStream_t stream) {
    const float* img_embed = (const float*)d_in[0];   // (128, 36, 1024)
    const float* cap_embed = (const float*)d_in[1];   // (32, 50, 1024)
    const int*   lens      = (const int*)  d_in[2];   // (32,)
    const float* red_w     = (const float*)d_in[3];   // (1024, 256)
    const float* red_b     = (const float*)d_in[4];   // (256,)
    const float* proj_w    = (const float*)d_in[5];   // (256, 196608)
    const float* proj_b    = (const float*)d_in[6];   // (196608,)
    float* out = (float*)d_out;                        // (128, 32)

    char* ws = (char*)d_ws;
    unsigned short* Wp2F   = (unsigned short*)(ws);                    // 12,582,912 B
    float* cap_repr  = (float*)(ws + 22020096);                        //    131,072 B
    float* cap_act   = (float*)(ws + 22151168);                        //    131,072 B
    float* qT        = (float*)(ws + 22282240);                        //     32,768 B
    float* norm_capr = (float*)(ws + 22315008);                        //        512 B
    float* part_dot  = (float*)(ws + 22315520);                        //    262,144 B
    float* part_ss   = (float*)(ws + 22577664);                        //    262,144 B

    hipLaunchKernelGGL(cap_mean_kernel, dim3(BC), dim3(256), 0, stream,
                       cap_embed, lens, cap_repr, cap_act, norm_capr);
    hipLaunchKernelGGL(q_kernel, dim3(8, BC), dim3(256), 0, stream,
                       cap_repr, red_w, red_b, qT);
    hipLaunchKernelGGL(wgen6_kernel, dim3(1024), dim3(192), 0, stream,
                       qT, proj_w, proj_b, Wp2F);
    hipLaunchKernelGGL(conv4b_kernel, dim3(NGROUPS, 16, 2), dim3(192), 0, stream,
                       img_embed, Wp2F, cap_repr, cap_act, part_dot, part_ss);
    hipLaunchKernelGGL(final_kernel, dim3(16), dim3(256), 0, stream,
                       part_dot, part_ss, norm_capr, out);
}